// Round 6
// baseline (316.871 us; speedup 1.0000x reference)
//
#include <hip/hip_runtime.h>
#include <math.h>

// Single-query attention, N=128, T=2048, D=512, fp32, length-masked.
// Masked t >= len: energy -1e9 -> expf == 0 exactly -> skip K/V reads there.
//
// R6: ONE kernel. Each 64-lane wave owns a 64-row chunk (pair-row streaming,
// online softmax, lane-uniform state -> no cross-wave combine, no barriers in
// the hot path). Per-batch finalization via last-ticket: after writing its
// partial, each wave atomicAdd's a per-batch counter; the wave drawing the
// last ticket combines all chunk partials (fixed order -> deterministic) and
// writes ctx row + mask row. Counters zeroed by hipMemsetAsync each call.

#define N_DIM 128
#define T_DIM 2048
#define D_DIM 512
#define TCHUNK 64
#define MAXCHUNK (N_DIM * (T_DIM / TCHUNK))  // 4096
#define NBLOCK (MAXCHUNK / 4)                // 1024 blocks x 4 waves

__device__ __forceinline__ float dot8(const float4 q0, const float4 q1,
                                      const float4 k0, const float4 k1) {
  return q0.x * k0.x + q0.y * k0.y + q0.z * k0.z + q0.w * k0.w +
         q1.x * k1.x + q1.y * k1.y + q1.z * k1.z + q1.w * k1.w;
}

__global__ __launch_bounds__(256, 4) void fused_attn_kernel(
    const float* __restrict__ Q, const float* __restrict__ K,
    const float* __restrict__ V, const int* __restrict__ lens,
    float* __restrict__ part, float* __restrict__ ms,
    int* __restrict__ cnt, float* __restrict__ ctx,
    float* __restrict__ mask_out) {
  const int tid = threadIdx.x;
  const int lane = tid & 63;
  const int wave = tid >> 6;

  // ---- Per-block prefix scan of chunk counts (maps wave id -> (n, c)).
  __shared__ int pfxL[N_DIM + 1];
  __shared__ int scanS[N_DIM];
  if (tid < N_DIM) scanS[tid] = (lens[tid] + TCHUNK - 1) >> 6;
  __syncthreads();
  for (int off = 1; off < N_DIM; off <<= 1) {
    int t = 0;
    if (tid < N_DIM && tid >= off) t = scanS[tid - off];
    __syncthreads();
    if (tid < N_DIM) scanS[tid] += t;
    __syncthreads();
  }
  if (tid < N_DIM) pfxL[tid + 1] = scanS[tid];
  if (tid == 0) pfxL[0] = 0;
  __syncthreads();

  const int total = pfxL[N_DIM];
  const int b = blockIdx.x * 4 + wave;  // global chunk id for this wave
  if (b >= total) return;

  int lo = 0, hi = N_DIM;  // pfxL[lo] <= b < pfxL[hi]
  while (hi - lo > 1) {
    const int mid = (lo + hi) >> 1;
    if (pfxL[mid] <= b) lo = mid; else hi = mid;
  }
  const int n = lo;
  const int c = b - pfxL[lo];
  const int base = pfxL[lo];
  const int len = lens[n];
  const int t0 = c * TCHUNK;
  const int nvalid = min(TCHUNK, len - t0);  // >= 1
  const int nc = (len + TCHUNK - 1) >> 6;

  const float4* Qv = (const float4*)(Q + (size_t)n * D_DIM);
  const float4 q0 = Qv[lane];
  const float4 q1 = Qv[64 + lane];
  const float4* Kb = (const float4*)(K + ((size_t)n * T_DIM + t0) * D_DIM);
  const float4* Vb = (const float4*)(V + ((size_t)n * T_DIM + t0) * D_DIM);

  float m = -INFINITY, ssum = 0.0f;
  float4 a0 = make_float4(0.f, 0.f, 0.f, 0.f);
  float4 a1 = make_float4(0.f, 0.f, 0.f, 0.f);

  // Pair rows (tt, tt+1), step 2, 1-pair prefetch. Row tt+1 may exceed nvalid
  // but never the array (chunk rows all < T_DIM) -> finite, killed by pB=0.
  float4 ka0 = Kb[lane],       ka1 = Kb[64 + lane];
  float4 kb0 = Kb[128 + lane], kb1 = Kb[192 + lane];
  float4 va0 = Vb[lane],       va1 = Vb[64 + lane];
  float4 vb0 = Vb[128 + lane], vb1 = Vb[192 + lane];

  for (int tt = 0; tt < nvalid; tt += 2) {
    const bool pre = (tt + 2 < nvalid);  // wave-uniform
    float4 nka0, nka1, nkb0, nkb1, nva0, nva1, nvb0, nvb1;
    if (pre) {
      const size_t o = (size_t)(tt + 2) * 128;
      nka0 = Kb[o + lane];       nka1 = Kb[o + 64 + lane];
      nkb0 = Kb[o + 128 + lane]; nkb1 = Kb[o + 192 + lane];
      nva0 = Vb[o + lane];       nva1 = Vb[o + 64 + lane];
      nvb0 = Vb[o + 128 + lane]; nvb1 = Vb[o + 192 + lane];
    }

    float eA = dot8(q0, q1, ka0, ka1);
    float eB = dot8(q0, q1, kb0, kb1);
#pragma unroll
    for (int off = 32; off; off >>= 1) {
      eA += __shfl_xor(eA, off, 64);
      eB += __shfl_xor(eB, off, 64);
    }
    if (tt + 1 >= nvalid) eB = -INFINITY;  // odd tail

    const float mNew = fmaxf(m, fmaxf(eA, eB));
    const float sc = __expf(m - mNew);     // first iter: expf(-inf) = 0
    const float pA = __expf(eA - mNew);
    const float pB = __expf(eB - mNew);    // eB=-inf -> 0
    m = mNew;
    ssum = ssum * sc + pA + pB;
    a0.x = a0.x * sc + pA * va0.x + pB * vb0.x;
    a0.y = a0.y * sc + pA * va0.y + pB * vb0.y;
    a0.z = a0.z * sc + pA * va0.z + pB * vb0.z;
    a0.w = a0.w * sc + pA * va0.w + pB * vb0.w;
    a1.x = a1.x * sc + pA * va1.x + pB * vb1.x;
    a1.y = a1.y * sc + pA * va1.y + pB * vb1.y;
    a1.z = a1.z * sc + pA * va1.z + pB * vb1.z;
    a1.w = a1.w * sc + pA * va1.w + pB * vb1.w;

    if (pre) {
      ka0 = nka0; ka1 = nka1; kb0 = nkb0; kb1 = nkb1;
      va0 = nva0; va1 = nva1; vb0 = nvb0; vb1 = nvb1;
    }
  }

  // ---- Publish chunk partial (m, ssum are lane-uniform; acc is the row).
  {
    float4* pr = (float4*)(part + (size_t)b * D_DIM);
    pr[lane] = a0;
    pr[64 + lane] = a1;
    if (lane == 0) { ms[b * 2] = m; ms[b * 2 + 1] = ssum; }
  }

  // ---- Ticket: last wave for batch n does the combine (deterministic:
  // fixed summation order over c, independent of which wave runs it).
  __threadfence();  // release partial writes before the ticket
  int ticket = 0;
  if (lane == 0) ticket = atomicAdd(&cnt[n], 1);
  ticket = __shfl(ticket, 0, 64);
  if (ticket != nc - 1) return;
  __threadfence();  // acquire other waves' partial writes

  float M = -INFINITY;
  for (int cc = 0; cc < nc; ++cc) M = fmaxf(M, ms[(base + cc) * 2]);
  float S = 0.0f;
  for (int cc = 0; cc < nc; ++cc)
    S += ms[(base + cc) * 2 + 1] * __expf(ms[(base + cc) * 2] - M);
  const float invS = 1.0f / S;

  float4 r0 = make_float4(0.f, 0.f, 0.f, 0.f);
  float4 r1 = make_float4(0.f, 0.f, 0.f, 0.f);
  for (int cc = 0; cc < nc; ++cc) {
    const float w = __expf(ms[(base + cc) * 2] - M) * invS;
    const float4* pr = (const float4*)(part + (size_t)(base + cc) * D_DIM);
    const float4 p0 = pr[lane];
    const float4 p1 = pr[64 + lane];
    r0.x = fmaf(w, p0.x, r0.x); r0.y = fmaf(w, p0.y, r0.y);
    r0.z = fmaf(w, p0.z, r0.z); r0.w = fmaf(w, p0.w, r0.w);
    r1.x = fmaf(w, p1.x, r1.x); r1.y = fmaf(w, p1.y, r1.y);
    r1.z = fmaf(w, p1.z, r1.z); r1.w = fmaf(w, p1.w, r1.w);
  }
  float4* cr = (float4*)(ctx + (size_t)n * D_DIM);
  cr[lane] = r0;
  cr[64 + lane] = r1;

  // Mask row for batch n: 2048 floats = 8 float4 per lane, coalesced.
  float4* mr = (float4*)(mask_out + (size_t)n * T_DIM);
#pragma unroll
  for (int j = 0; j < 8; ++j) {
    const int tb = (j * 64 + lane) * 4;
    float4 mv;
    mv.x = (tb + 0 >= len) ? 1.0f : 0.0f;
    mv.y = (tb + 1 >= len) ? 1.0f : 0.0f;
    mv.z = (tb + 2 >= len) ? 1.0f : 0.0f;
    mv.w = (tb + 3 >= len) ? 1.0f : 0.0f;
    mr[j * 64 + lane] = mv;
  }
}

extern "C" void kernel_launch(void* const* d_in, const int* in_sizes, int n_in,
                              void* d_out, int out_size, void* d_ws, size_t ws_size,
                              hipStream_t stream) {
  const float* Q = (const float*)d_in[0];     // [128][512]
  const float* K = (const float*)d_in[1];     // [128][2048][512]
  const float* V = (const float*)d_in[2];     // [128][2048][512]
  const int* lens = (const int*)d_in[3];      // [128]

  float* out = (float*)d_out;
  float* ctx = out;                           // [128][512]
  float* mask_out = out + N_DIM * D_DIM;      // [128][2048]

  float* part = (float*)d_ws;                     // [MAXCHUNK][512] (8 MB)
  float* ms = part + (size_t)MAXCHUNK * D_DIM;    // [MAXCHUNK][2]
  int* cnt = (int*)(ms + (size_t)MAXCHUNK * 2);   // [128]

  hipMemsetAsync(cnt, 0, N_DIM * sizeof(int), stream);
  fused_attn_kernel<<<dim3(NBLOCK), 256, 0, stream>>>(
      Q, K, V, lens, part, ms, cnt, ctx, mask_out);
}